// Round 2
// 188.871 us; speedup vs baseline: 1.1040x; 1.1040x over previous
//
#include <hip/hip_runtime.h>
#include <hip/hip_bf16.h>

#define N_ATOMS 50000
#define DEG 16
#define N_MOL 1000
#define NA 23
#define NB 7
#define O0 32
#define O1 12
#define O2 8
#define OZ 21          // folded output width: w0f(7) | w1f(7) | w2f(7), pad to 32
#define NT 2           // N-tiles of 16
#define ZROW 64        // floats per z-row: [b*8+c] c=0..7; c8 at 56+b; [63]=0
#define NPW 4          // nodes per wave in k2
#define VFRAG_N 896    // 14 fragments * 64 lanes, short8 each (14336 B)

typedef __attribute__((ext_vector_type(8))) short short8;
typedef __attribute__((ext_vector_type(4))) float floatx4;

__device__ __forceinline__ unsigned short bfbits(float f) {  // f32 -> bf16 RNE
    unsigned u = __float_as_uint(f);
    u += 0x7FFFu + ((u >> 16) & 1u);
    return (unsigned short)(u >> 16);
}
__device__ __forceinline__ float bf_lo(unsigned u) { return __uint_as_float(u << 16); }
__device__ __forceinline__ float bf_hi(unsigned u) { return __uint_as_float(u & 0xFFFF0000u); }
__device__ __forceinline__ float wred4(float v) {  // sum over the 4 quads
    v += __shfl_xor(v, 16, 64); v += __shfl_xor(v, 32, 64); return v;
}

// ---------------- K_prep: zero out + folded Vfrag (W1*W2) + x_bf + pos4 ------
// V[a,b',o21] = norm * sum_k W1_x[a,b',k] * W2_x[k,b]; norms (n1, c_x, q=0.25)
// folded in. o21: 0..6 -> e0 path, 7..13 -> e1, 14..20 -> e2.
__global__ void k_prep(const float* __restrict__ W1_0, const float* __restrict__ W1_1,
                       const float* __restrict__ W1_2,
                       const float* __restrict__ W2_0, const float* __restrict__ W2_1,
                       const float* __restrict__ W2_2,
                       const float* __restrict__ x, const float* __restrict__ pos,
                       unsigned short* __restrict__ Vfrag,
                       unsigned short* __restrict__ x_bf, float4* __restrict__ pos4,
                       float* __restrict__ out) {
    int idx = blockIdx.x * 256 + threadIdx.x;
    if (idx < N_MOL) out[idx] = 0.0f;
    if (idx < VFRAG_N * 8) {
        int j    = idx & 7;
        int lane = (idx >> 3) & 63;
        int st   = idx >> 9;           // 0..13 = s*NT+t
        int s = st >> 1, t = st & 1;
        int a = (lane >> 4) * 8 + j, o = t * 16 + (lane & 15);
        float val = 0.f;
        if (a < NA && o < OZ) {
            const float n1 = 0.07881104062391006f;   // 1/sqrt(23*7)
            const float q  = 0.25f;                  // inv_sqrt_deg (deg==16)
            float acc = 0.f;
            if (o < 7) {
                const float c0 = 0.06681531047810609f;   // 1/sqrt(32*7)
                const float* w1 = W1_0 + (a * NB + s) * O0;
                for (int k = 0; k < O0; k++) acc += w1[k] * W2_0[k * NB + o];
                val = acc * (n1 * c0 * q);
            } else if (o < 14) {
                const float c1 = 0.06299407883487121f;   // 1/(sqrt(12*7)*sqrt(3))
                const float* w1 = W1_1 + (a * NB + s) * O1;
                for (int k = 0; k < O1; k++) acc += w1[k] * W2_1[k * NB + (o - 7)];
                val = acc * (n1 * c1 * q);
            } else {
                const float c2 = 0.05976143046671968f;   // 1/(sqrt(8*7)*sqrt(5))
                const float* w1 = W1_2 + (a * NB + s) * O2;
                for (int k = 0; k < O2; k++) acc += w1[k] * W2_2[k * NB + (o - 14)];
                val = acc * (n1 * c2 * q);
            }
        }
        Vfrag[idx] = bfbits(val);
    }
    if (idx < N_ATOMS) {
        float4 p; p.x = pos[idx * 3 + 0]; p.y = pos[idx * 3 + 1];
        p.z = pos[idx * 3 + 2]; p.w = 0.f;
        pos4[idx] = p;
    }
    if (idx < N_ATOMS * 32) {
        int n = idx >> 5, a = idx & 31;
        x_bf[idx] = bfbits((a < NA) ? x[n * NA + a] : 0.f);
    }
}

// ---------------- K2: per-node MFMA GEMM (N=21 folded); z-row epilogue -------
__global__ __launch_bounds__(256, 5) void k2_s(const float4* __restrict__ pos4,
        const unsigned short* __restrict__ x_bf, const float* __restrict__ edge_attr,
        const int* __restrict__ edge_src, const unsigned short* __restrict__ Vfrag,
        float* __restrict__ zbuf) {
    __shared__ short8 wfrag[VFRAG_N];          // 14336 B, shared by 4 waves
    __shared__ float hbuf[4][16][8];
    const int tid  = threadIdx.x;
    const int wid  = tid >> 6;
    const int lane = tid & 63;
    const int lcol = lane & 15;
    const int quad = lane >> 4;

    {   // cooperative stage of the prebuilt folded-weight fragments
        uint4* dst = (uint4*)wfrag;
        const uint4* src4 = (const uint4*)Vfrag;
        for (int i = tid; i < VFRAG_N; i += 256) dst[i] = src4[i];
    }
    __syncthreads();

    const int wgid = __builtin_amdgcn_readfirstlane(blockIdx.x * 4 + wid);
    const int base = wgid * NPW;
    if (base >= N_ATOMS) return;

    float (*hb)[8] = hbuf[wid];
    const float s3 = 1.7320508075688772f, s15 = 3.872983346207417f;
    const float s5h = 1.118033988749895f, s15h = 1.9364916731037085f;

    auto clampn = [&](int i) { int nn = base + i; return nn < N_ATOMS ? nn : N_ATOMS - 1; };
    int s0v = edge_src[clampn(0) * DEG + lcol];
    int s1v = edge_src[clampn(1) * DEG + lcol];
    uint4 xu0 = *(const uint4*)(x_bf + s0v * 32 + quad * 8);
    float4 pp0 = pos4[s0v];
    float e0v[NB];
    {
        const float* p = edge_attr + ((size_t)clampn(0) * DEG + lcol) * NB;
        #pragma unroll
        for (int b = 0; b < NB; b++) e0v[b] = p[b];
    }

    #pragma unroll 1
    for (int i = 0; i < NPW; i++) {
        const int n = base + i;
        if (n >= N_ATOMS) break;
        // ---- prefetch next stage ----
        int s2v = edge_src[clampn(i + 2 < NPW ? i + 2 : i) * DEG + lcol];
        uint4 xu1 = *(const uint4*)(x_bf + s1v * 32 + quad * 8);
        float4 pp1 = pos4[s1v];
        float e1v[NB];
        {
            const float* p = edge_attr + ((size_t)clampn(i + 1 < NPW ? i + 1 : i) * DEG + lcol) * NB;
            #pragma unroll
            for (int b = 0; b < NB; b++) e1v[b] = p[b];
        }
        // ---- unpack this node's x slice ----
        float xf[8];
        xf[0] = bf_lo(xu0.x); xf[1] = bf_hi(xu0.x);
        xf[2] = bf_lo(xu0.y); xf[3] = bf_hi(xu0.y);
        xf[4] = bf_lo(xu0.z); xf[5] = bf_hi(xu0.z);
        xf[6] = bf_lo(xu0.w); xf[7] = bf_hi(xu0.w);

        // ---- h-factors for node n (lanes 0..15): [sh1(3), sh2(5)] ----
        const float4 pd = pos4[n];
        if (lane < 16) {
            const float vx = pp0.x - pd.x, vy = pp0.y - pd.y, vz = pp0.z - pd.z;
            hb[lane][0] = s3 * vx;  hb[lane][1] = s3 * vy;  hb[lane][2] = s3 * vz;
            hb[lane][3] = s15 * vx * vy;
            hb[lane][4] = s15 * vy * vz;
            hb[lane][5] = s5h * (2.f * vz * vz - vx * vx - vy * vy);
            hb[lane][6] = s15 * vx * vz;
            hb[lane][7] = s15h * (vx * vx - vy * vy);
        }
        // ---- MFMA: 7 K-steps x 2 N-tiles (folded weights) ----
        floatx4 acc0 = {0.f,0.f,0.f,0.f}, acc1 = {0.f,0.f,0.f,0.f};
        #pragma unroll
        for (int s = 0; s < 7; s++) {
            const float eb = e0v[s];
            union { short8 v; unsigned u[4]; } af;
            #pragma unroll
            for (int j = 0; j < 8; j += 2) {
                float2 pr; pr.x = xf[j] * eb; pr.y = xf[j + 1] * eb;
                __hip_bfloat162 bb = __float22bfloat162_rn(pr);
                af.u[j >> 1] = *(unsigned*)&bb;
            }
            acc0 = __builtin_amdgcn_mfma_f32_16x16x32_bf16(af.v, wfrag[(s*NT+0)*64 + lane], acc0, 0, 0, 0);
            acc1 = __builtin_amdgcn_mfma_f32_16x16x32_bf16(af.v, wfrag[(s*NT+1)*64 + lane], acc1, 0, 0, 0);
        }
        // ---- epilogue: produce z-row (63 f32) directly ----
        // acc cols: o=lcol (acc0), o=16+lcol (acc1); lane's D-edges e=quad*4+r.
        // z0[b]=sum_e w0f ; z1[b,m]=sum_e w1f*h1[m] ; z2[b,m]=sum_e w2f*h2[m]
        float4 hA[4], hB[4];
        #pragma unroll
        for (int r = 0; r < 4; r++) {
            int e = quad * 4 + r;
            hA[r] = *(const float4*)&hb[e][0];   // sh1 x,y,z | sh2 m0
            hB[r] = *(const float4*)&hb[e][4];   // sh2 m1..m4
        }
        float* sr = zbuf + (size_t)n * ZROW;
        const bool useA = (lcol >= 14);          // z2 source: acc0 cols 14,15 else acc1 cols 0..4
        float v0 = acc0[0] + acc0[1] + acc0[2] + acc0[3];
        float u0 = 0.f, u1 = 0.f, u2 = 0.f;
        float t0 = 0.f, t1 = 0.f, t2 = 0.f, t3 = 0.f, t4 = 0.f;
        #pragma unroll
        for (int r = 0; r < 4; r++) {
            float m0 = acc0[r], m1 = acc1[r];
            u0 += m0 * hA[r].x; u1 += m0 * hA[r].y; u2 += m0 * hA[r].z;
            float mz = useA ? m0 : m1;
            t0 += mz * hA[r].w; t1 += mz * hB[r].x; t2 += mz * hB[r].y;
            t3 += mz * hB[r].z; t4 += mz * hB[r].w;
        }
        v0 = wred4(v0);
        u0 = wred4(u0); u1 = wred4(u1); u2 = wred4(u2);
        t0 = wred4(t0); t1 = wred4(t1); t2 = wred4(t2); t3 = wred4(t3); t4 = wred4(t4);
        if (quad == 0) {
            if (lcol < 7) sr[lcol * 8] = v0;                        // c=0
            else if (lcol < 14) {                                   // c=1..3 (sh1)
                int b = lcol - 7;
                sr[b * 8 + 1] = u0; sr[b * 8 + 2] = u1; sr[b * 8 + 3] = u2;
            }
            if (lcol >= 14 || lcol < 5) {                           // c=4..8 (sh2)
                int b = useA ? (lcol - 14) : (lcol + 2);
                sr[b * 8 + 4] = t0; sr[b * 8 + 5] = t1; sr[b * 8 + 6] = t2;
                sr[b * 8 + 7] = t3; sr[56 + b] = t4;
            }
            if (lcol == 5) sr[63] = 0.f;   // pad (read by k3 r=3, killed by ea1=0; must be finite)
        }
        // ---- rotate pipeline ----
        s0v = s1v; s1v = s2v;
        xu0 = xu1; pp0 = pp1;
        #pragma unroll
        for (int b = 0; b < NB; b++) e0v[b] = e1v[b];
    }
}

// ---------------- K3: one node per wave; quad per edge; z-row gather + dot ---
// per edge: e = sum_b ea[b] * ( z[b,0] + sum_m h[m+1]*z[b,m+1] + h8*c8[b] )
__global__ __launch_bounds__(256, 8) void k3_fused(const float4* __restrict__ pos4,
        const float* __restrict__ edge_attr, const int* __restrict__ edge_src,
        const float* __restrict__ zbuf, float* __restrict__ out) {
    const int tid  = threadIdx.x;
    const int wid  = tid >> 6;
    const int lane = tid & 63;
    const int n = __builtin_amdgcn_readfirstlane(blockIdx.x * 4 + wid);
    const int k = lane >> 2, r = lane & 3;     // edge k, b-pair r -> b=2r,2r+1

    const int s = edge_src[n * DEG + k];
    const float* zr = zbuf + (size_t)s * ZROW;
    const float* zp = zr + 16 * r;
    float4 Z0 = *(const float4*)(zp);          // b0 codes 0..3
    float4 Z1 = *(const float4*)(zp + 4);      // b0 codes 4..7
    float4 Z2 = *(const float4*)(zp + 8);      // b1 codes 0..3
    float4 Z3 = *(const float4*)(zp + 12);     // b1 codes 4..7
    float2 C8 = *(const float2*)(zr + 56 + 2 * r);   // c8[b0], c8[b1]
    const float* eap = edge_attr + ((size_t)n * DEG + k) * NB;
    float ea0 = eap[2 * r];
    float ea1 = (r < 3) ? eap[2 * r + 1] : 0.f;      // b=7 pad lane

    float4 ps = pos4[s];
    float4 pd = pos4[n];
    const float vx = ps.x - pd.x, vy = ps.y - pd.y, vz = ps.z - pd.z;
    const float s3 = 1.7320508075688772f, s15 = 3.872983346207417f;
    const float s5h = 1.118033988749895f, s15h = 1.9364916731037085f;
    const float h1 = s3 * vx, h2 = s3 * vy, h3 = s3 * vz;
    const float h4 = s15 * vx * vy, h5 = s15 * vy * vz;
    const float h6 = s5h * (2.f * vz * vz - vx * vx - vy * vy);
    const float h7 = s15 * vx * vz, h8 = s15h * (vx * vx - vy * vy);

    float t0 = Z0.x + h1 * Z0.y + h2 * Z0.z + h3 * Z0.w
             + h4 * Z1.x + h5 * Z1.y + h6 * Z1.z + h7 * Z1.w + h8 * C8.x;
    float t1 = Z2.x + h1 * Z2.y + h2 * Z2.z + h3 * Z2.w
             + h4 * Z3.x + h5 * Z3.y + h6 * Z3.z + h7 * Z3.w + h8 * C8.y;
    float acc = ea0 * t0 + ea1 * t1;

    #pragma unroll
    for (int off = 32; off >= 1; off >>= 1) acc += __shfl_xor(acc, off, 64);
    if (lane == 0)
        atomicAdd(out + n / 50, acc * 0.035355339059327376f);  // 0.25/sqrt(50)
}

extern "C" void kernel_launch(void* const* d_in, const int* in_sizes, int n_in,
                              void* d_out, int out_size, void* d_ws, size_t ws_size,
                              hipStream_t stream) {
    const float* pos  = (const float*)d_in[0];
    const float* x    = (const float*)d_in[1];
    const float* ea   = (const float*)d_in[2];
    const float* W1_0 = (const float*)d_in[3];
    const float* W1_1 = (const float*)d_in[4];
    const float* W1_2 = (const float*)d_in[5];
    const float* W2_0 = (const float*)d_in[6];
    const float* W2_1 = (const float*)d_in[7];
    const float* W2_2 = (const float*)d_in[8];
    const int*   esrc = (const int*)d_in[9];
    float* out = (float*)d_out;

    char* ws = (char*)d_ws;
    unsigned short* Vfrag = (unsigned short*)ws;                         // 14336 B
    float*          zbuf  = (float*)(ws + 32768);                        // 12.8 MB
    unsigned short* x_bf  = (unsigned short*)(ws + 32768 + 12800000);    // 3.2 MB
    float4*         pos4  = (float4*)(ws + 32768 + 12800000 + 3200000);  // 800 KB

    hipLaunchKernelGGL(k_prep, dim3((N_ATOMS * 32 + 255) / 256), dim3(256), 0, stream,
                       W1_0, W1_1, W1_2, W2_0, W2_1, W2_2, x, pos, Vfrag, x_bf, pos4, out);
    hipLaunchKernelGGL(k2_s, dim3((N_ATOMS / NPW + 3) / 4), dim3(256), 0, stream,
                       pos4, x_bf, ea, esrc, Vfrag, zbuf);
    hipLaunchKernelGGL(k3_fused, dim3(N_ATOMS / 4), dim3(256), 0, stream,
                       pos4, ea, esrc, zbuf, out);
}

// Round 3
// 184.902 us; speedup vs baseline: 1.1277x; 1.0215x over previous
//
#include <hip/hip_runtime.h>
#include <hip/hip_bf16.h>

#define N_ATOMS 50000
#define DEG 16
#define N_MOL 1000
#define NA 23
#define NB 7
#define O0 32
#define O1 12
#define O2 8
#define OZ 21          // folded output width: w0f(7) | w1f(7) | w2f(7), pad to 32
#define NT 2           // N-tiles of 16
#define ZROW 64        // bf16 per z-row: [b*8+c] c=0..7; c8 at 56+b; [63]=0  (128 B = 1 line)
#define NPW 4          // nodes per wave in k2
#define VFRAG_N 896    // 14 fragments * 64 lanes, short8 each (14336 B)

typedef __attribute__((ext_vector_type(8))) short short8;
typedef __attribute__((ext_vector_type(4))) float floatx4;

__device__ __forceinline__ unsigned short bfbits(float f) {  // f32 -> bf16 RNE
    unsigned u = __float_as_uint(f);
    u += 0x7FFFu + ((u >> 16) & 1u);
    return (unsigned short)(u >> 16);
}
__device__ __forceinline__ float bf_lo(unsigned u) { return __uint_as_float(u << 16); }
__device__ __forceinline__ float bf_hi(unsigned u) { return __uint_as_float(u & 0xFFFF0000u); }
__device__ __forceinline__ float wred4(float v) {  // sum over the 4 quads
    v += __shfl_xor(v, 16, 64); v += __shfl_xor(v, 32, 64); return v;
}

// ---------------- K_prep: zero out + folded Vfrag (W1*W2) + x_bf + pos4 ------
// V[a,b',o21] = norm * sum_k W1_x[a,b',k] * W2_x[k,b]; norms (n1, c_x, q=0.25)
// folded in. o21: 0..6 -> e0 path, 7..13 -> e1, 14..20 -> e2.
__global__ void k_prep(const float* __restrict__ W1_0, const float* __restrict__ W1_1,
                       const float* __restrict__ W1_2,
                       const float* __restrict__ W2_0, const float* __restrict__ W2_1,
                       const float* __restrict__ W2_2,
                       const float* __restrict__ x, const float* __restrict__ pos,
                       unsigned short* __restrict__ Vfrag,
                       unsigned short* __restrict__ x_bf, float4* __restrict__ pos4,
                       float* __restrict__ out) {
    int idx = blockIdx.x * 256 + threadIdx.x;
    if (idx < N_MOL) out[idx] = 0.0f;
    if (idx < VFRAG_N * 8) {
        int j    = idx & 7;
        int lane = (idx >> 3) & 63;
        int st   = idx >> 9;           // 0..13 = s*NT+t
        int s = st >> 1, t = st & 1;
        int a = (lane >> 4) * 8 + j, o = t * 16 + (lane & 15);
        float val = 0.f;
        if (a < NA && o < OZ) {
            const float n1 = 0.07881104062391006f;   // 1/sqrt(23*7)
            const float q  = 0.25f;                  // inv_sqrt_deg (deg==16)
            float acc = 0.f;
            if (o < 7) {
                const float c0 = 0.06681531047810609f;   // 1/sqrt(32*7)
                const float* w1 = W1_0 + (a * NB + s) * O0;
                for (int k = 0; k < O0; k++) acc += w1[k] * W2_0[k * NB + o];
                val = acc * (n1 * c0 * q);
            } else if (o < 14) {
                const float c1 = 0.06299407883487121f;   // 1/(sqrt(12*7)*sqrt(3))
                const float* w1 = W1_1 + (a * NB + s) * O1;
                for (int k = 0; k < O1; k++) acc += w1[k] * W2_1[k * NB + (o - 7)];
                val = acc * (n1 * c1 * q);
            } else {
                const float c2 = 0.05976143046671968f;   // 1/(sqrt(8*7)*sqrt(5))
                const float* w1 = W1_2 + (a * NB + s) * O2;
                for (int k = 0; k < O2; k++) acc += w1[k] * W2_2[k * NB + (o - 14)];
                val = acc * (n1 * c2 * q);
            }
        }
        Vfrag[idx] = bfbits(val);
    }
    if (idx < N_ATOMS) {
        float4 p; p.x = pos[idx * 3 + 0]; p.y = pos[idx * 3 + 1];
        p.z = pos[idx * 3 + 2]; p.w = 0.f;
        pos4[idx] = p;
    }
    if (idx < N_ATOMS * 32) {
        int n = idx >> 5, a = idx & 31;
        x_bf[idx] = bfbits((a < NA) ? x[n * NA + a] : 0.f);
    }
}

// ---------------- K2: per-node MFMA GEMM (N=21 folded); bf16 z-row epilogue --
__global__ __launch_bounds__(256, 5) void k2_s(const float4* __restrict__ pos4,
        const unsigned short* __restrict__ x_bf, const float* __restrict__ edge_attr,
        const int* __restrict__ edge_src, const unsigned short* __restrict__ Vfrag,
        unsigned short* __restrict__ zbuf) {
    __shared__ short8 wfrag[VFRAG_N];          // 14336 B, shared by 4 waves
    __shared__ float hbuf[4][16][8];
    const int tid  = threadIdx.x;
    const int wid  = tid >> 6;
    const int lane = tid & 63;
    const int lcol = lane & 15;
    const int quad = lane >> 4;

    {   // cooperative stage of the prebuilt folded-weight fragments
        uint4* dst = (uint4*)wfrag;
        const uint4* src4 = (const uint4*)Vfrag;
        for (int i = tid; i < VFRAG_N; i += 256) dst[i] = src4[i];
    }
    __syncthreads();

    const int wgid = __builtin_amdgcn_readfirstlane(blockIdx.x * 4 + wid);
    const int base = wgid * NPW;
    if (base >= N_ATOMS) return;

    float (*hb)[8] = hbuf[wid];
    const float s3 = 1.7320508075688772f, s15 = 3.872983346207417f;
    const float s5h = 1.118033988749895f, s15h = 1.9364916731037085f;

    auto clampn = [&](int i) { int nn = base + i; return nn < N_ATOMS ? nn : N_ATOMS - 1; };
    int s0v = edge_src[clampn(0) * DEG + lcol];
    int s1v = edge_src[clampn(1) * DEG + lcol];
    uint4 xu0 = *(const uint4*)(x_bf + s0v * 32 + quad * 8);
    float4 pp0 = pos4[s0v];
    float e0v[NB];
    {
        const float* p = edge_attr + ((size_t)clampn(0) * DEG + lcol) * NB;
        #pragma unroll
        for (int b = 0; b < NB; b++) e0v[b] = p[b];
    }

    #pragma unroll 1
    for (int i = 0; i < NPW; i++) {
        const int n = base + i;
        if (n >= N_ATOMS) break;
        // ---- prefetch next stage ----
        int s2v = edge_src[clampn(i + 2 < NPW ? i + 2 : i) * DEG + lcol];
        uint4 xu1 = *(const uint4*)(x_bf + s1v * 32 + quad * 8);
        float4 pp1 = pos4[s1v];
        float e1v[NB];
        {
            const float* p = edge_attr + ((size_t)clampn(i + 1 < NPW ? i + 1 : i) * DEG + lcol) * NB;
            #pragma unroll
            for (int b = 0; b < NB; b++) e1v[b] = p[b];
        }
        // ---- unpack this node's x slice ----
        float xf[8];
        xf[0] = bf_lo(xu0.x); xf[1] = bf_hi(xu0.x);
        xf[2] = bf_lo(xu0.y); xf[3] = bf_hi(xu0.y);
        xf[4] = bf_lo(xu0.z); xf[5] = bf_hi(xu0.z);
        xf[6] = bf_lo(xu0.w); xf[7] = bf_hi(xu0.w);

        // ---- h-factors for node n (lanes 0..15): [sh1(3), sh2(5)] ----
        const float4 pd = pos4[n];
        if (lane < 16) {
            const float vx = pp0.x - pd.x, vy = pp0.y - pd.y, vz = pp0.z - pd.z;
            hb[lane][0] = s3 * vx;  hb[lane][1] = s3 * vy;  hb[lane][2] = s3 * vz;
            hb[lane][3] = s15 * vx * vy;
            hb[lane][4] = s15 * vy * vz;
            hb[lane][5] = s5h * (2.f * vz * vz - vx * vx - vy * vy);
            hb[lane][6] = s15 * vx * vz;
            hb[lane][7] = s15h * (vx * vx - vy * vy);
        }
        // ---- MFMA: 7 K-steps x 2 N-tiles (folded weights) ----
        floatx4 acc0 = {0.f,0.f,0.f,0.f}, acc1 = {0.f,0.f,0.f,0.f};
        #pragma unroll
        for (int s = 0; s < 7; s++) {
            const float eb = e0v[s];
            union { short8 v; unsigned u[4]; } af;
            #pragma unroll
            for (int j = 0; j < 8; j += 2) {
                float2 pr; pr.x = xf[j] * eb; pr.y = xf[j + 1] * eb;
                __hip_bfloat162 bb = __float22bfloat162_rn(pr);
                af.u[j >> 1] = *(unsigned*)&bb;
            }
            acc0 = __builtin_amdgcn_mfma_f32_16x16x32_bf16(af.v, wfrag[(s*NT+0)*64 + lane], acc0, 0, 0, 0);
            acc1 = __builtin_amdgcn_mfma_f32_16x16x32_bf16(af.v, wfrag[(s*NT+1)*64 + lane], acc1, 0, 0, 0);
        }
        // ---- epilogue: produce bf16 z-row (63 vals + pad) directly ----
        // acc cols: o=lcol (acc0), o=16+lcol (acc1); lane's D-edges e=quad*4+r.
        float4 hA[4], hB[4];
        #pragma unroll
        for (int r = 0; r < 4; r++) {
            int e = quad * 4 + r;
            hA[r] = *(const float4*)&hb[e][0];   // sh1 x,y,z | sh2 m0
            hB[r] = *(const float4*)&hb[e][4];   // sh2 m1..m4
        }
        unsigned short* sr = zbuf + (size_t)n * ZROW;
        const bool useA = (lcol >= 14);          // z2 source: acc0 cols 14,15 else acc1 cols 0..4
        float v0 = acc0[0] + acc0[1] + acc0[2] + acc0[3];
        float u0 = 0.f, u1 = 0.f, u2 = 0.f;
        float t0 = 0.f, t1 = 0.f, t2 = 0.f, t3 = 0.f, t4 = 0.f;
        #pragma unroll
        for (int r = 0; r < 4; r++) {
            float m0 = acc0[r], m1 = acc1[r];
            u0 += m0 * hA[r].x; u1 += m0 * hA[r].y; u2 += m0 * hA[r].z;
            float mz = useA ? m0 : m1;
            t0 += mz * hA[r].w; t1 += mz * hB[r].x; t2 += mz * hB[r].y;
            t3 += mz * hB[r].z; t4 += mz * hB[r].w;
        }
        v0 = wred4(v0);
        u0 = wred4(u0); u1 = wred4(u1); u2 = wred4(u2);
        t0 = wred4(t0); t1 = wred4(t1); t2 = wred4(t2); t3 = wred4(t3); t4 = wred4(t4);
        if (quad == 0) {
            if (lcol < 7) sr[lcol * 8] = bfbits(v0);                // c=0
            else if (lcol < 14) {                                   // c=1..3 (sh1)
                int b = lcol - 7;
                sr[b * 8 + 1] = bfbits(u0); sr[b * 8 + 2] = bfbits(u1); sr[b * 8 + 3] = bfbits(u2);
            }
            if (lcol >= 14 || lcol < 5) {                           // c=4..8 (sh2)
                int b = useA ? (lcol - 14) : (lcol + 2);
                sr[b * 8 + 4] = bfbits(t0); sr[b * 8 + 5] = bfbits(t1); sr[b * 8 + 6] = bfbits(t2);
                sr[b * 8 + 7] = bfbits(t3); sr[56 + b] = bfbits(t4);
            }
            if (lcol == 5) sr[63] = 0;   // pad
        }
        // ---- rotate pipeline ----
        s0v = s1v; s1v = s2v;
        xu0 = xu1; pp0 = pp1;
        #pragma unroll
        for (int b = 0; b < NB; b++) e0v[b] = e1v[b];
    }
}

// ---------------- K3: one edge per lane; 4 nodes per wave; bf16 z gather -----
// per edge: e = sum_b ea[b] * ( z[b,0] + sum_m h[m]*z[b,m] + h8*c8[b] )
__global__ __launch_bounds__(256, 6) void k3_fused(const float4* __restrict__ pos4,
        const float* __restrict__ edge_attr, const int* __restrict__ edge_src,
        const unsigned short* __restrict__ zbuf, float* __restrict__ out) {
    const int tid  = threadIdx.x;
    const int wid  = tid >> 6;
    const int lane = tid & 63;
    const int g    = lane >> 4;                 // node within wave (0..3)
    const int k    = lane & 15;                 // edge
    const int n = __builtin_amdgcn_readfirstlane(blockIdx.x * 4 + wid) * 4 + g;

    const int s = edge_src[n * DEG + k];        // 64 consecutive ints -> coalesced
    const uint4* zr = (const uint4*)(zbuf + (size_t)s * ZROW);   // 128 B = 1 line
    uint4 zq[8];
    #pragma unroll
    for (int i = 0; i < 8; i++) zq[i] = zr[i];  // whole row in flight

    const float* eap = edge_attr + ((size_t)n * DEG + k) * NB;
    float4 e03 = *(const float4*)(eap);         // b0..b3 (4B-aligned ok)
    float2 e45 = *(const float2*)(eap + 4);
    float  e6  = eap[6];

    const float4 ps = pos4[s];
    const float4 pd = pos4[n];
    const float vx = ps.x - pd.x, vy = ps.y - pd.y, vz = ps.z - pd.z;
    const float s3 = 1.7320508075688772f, s15 = 3.872983346207417f;
    const float s5h = 1.118033988749895f, s15h = 1.9364916731037085f;
    const float h1 = s3 * vx, h2 = s3 * vy, h3 = s3 * vz;
    const float h4 = s15 * vx * vy, h5 = s15 * vy * vz;
    const float h6 = s5h * (2.f * vz * vz - vx * vx - vy * vy);
    const float h7 = s15 * vx * vz, h8 = s15h * (vx * vx - vy * vy);

    float eab[NB] = {e03.x, e03.y, e03.z, e03.w, e45.x, e45.y, e6};
    // c8 values: zq[7] holds [56..63] = c8[0..6] + pad
    float c8v[NB];
    c8v[0] = bf_lo(zq[7].x); c8v[1] = bf_hi(zq[7].x);
    c8v[2] = bf_lo(zq[7].y); c8v[3] = bf_hi(zq[7].y);
    c8v[4] = bf_lo(zq[7].z); c8v[5] = bf_hi(zq[7].z);
    c8v[6] = bf_lo(zq[7].w);

    float acc = 0.f;
    #pragma unroll
    for (int b = 0; b < NB; b++) {
        const uint4 z = zq[b];                  // [b*8 .. b*8+7]
        float t = bf_lo(z.x)
                + h1 * bf_hi(z.x) + h2 * bf_lo(z.y) + h3 * bf_hi(z.y)
                + h4 * bf_lo(z.z) + h5 * bf_hi(z.z) + h6 * bf_lo(z.w)
                + h7 * bf_hi(z.w) + h8 * c8v[b];
        acc += eab[b] * t;
    }

    // reduce within 16-lane group (edges of one node)
    acc += __shfl_xor(acc, 1, 64);
    acc += __shfl_xor(acc, 2, 64);
    acc += __shfl_xor(acc, 4, 64);
    acc += __shfl_xor(acc, 8, 64);
    if (k == 0)
        atomicAdd(out + n / 50, acc * 0.035355339059327376f);  // 0.25/sqrt(50)
}

extern "C" void kernel_launch(void* const* d_in, const int* in_sizes, int n_in,
                              void* d_out, int out_size, void* d_ws, size_t ws_size,
                              hipStream_t stream) {
    const float* pos  = (const float*)d_in[0];
    const float* x    = (const float*)d_in[1];
    const float* ea   = (const float*)d_in[2];
    const float* W1_0 = (const float*)d_in[3];
    const float* W1_1 = (const float*)d_in[4];
    const float* W1_2 = (const float*)d_in[5];
    const float* W2_0 = (const float*)d_in[6];
    const float* W2_1 = (const float*)d_in[7];
    const float* W2_2 = (const float*)d_in[8];
    const int*   esrc = (const int*)d_in[9];
    float* out = (float*)d_out;

    char* ws = (char*)d_ws;
    unsigned short* Vfrag = (unsigned short*)ws;                         // 14336 B
    unsigned short* zbuf  = (unsigned short*)(ws + 32768);               // 6.4 MB (bf16 rows)
    unsigned short* x_bf  = (unsigned short*)(ws + 32768 + 6400000);     // 3.2 MB
    float4*         pos4  = (float4*)(ws + 32768 + 6400000 + 3200000);   // 800 KB

    hipLaunchKernelGGL(k_prep, dim3((N_ATOMS * 32 + 255) / 256), dim3(256), 0, stream,
                       W1_0, W1_1, W1_2, W2_0, W2_1, W2_2, x, pos, Vfrag, x_bf, pos4, out);
    hipLaunchKernelGGL(k2_s, dim3((N_ATOMS / NPW + 3) / 4), dim3(256), 0, stream,
                       pos4, x_bf, ea, esrc, Vfrag, zbuf);
    hipLaunchKernelGGL(k3_fused, dim3(N_ATOMS / 16), dim3(256), 0, stream,
                       pos4, ea, esrc, zbuf, out);
}